// Round 2
// baseline (276.157 us; speedup 1.0000x reference)
//
#include <hip/hip_runtime.h>

typedef unsigned short u16;
typedef __attribute__((ext_vector_type(8))) short short8;
typedef __attribute__((ext_vector_type(4))) float f32x4;

// ---------- helpers ----------
__device__ inline u16 f2bf(float f) {
    union { float f; unsigned u; } v; v.f = f;
    unsigned u = v.u;
    unsigned r = (u + 0x7FFFu + ((u >> 16) & 1u)) >> 16;
    return (u16)r;
}
__device__ inline float bf2f(u16 h) {
    union { unsigned u; float f; } v; v.u = ((unsigned)h) << 16;
    return v.f;
}
__device__ inline float ftanh(float x) {
    float e = __expf(2.f * x);
    return 1.f - 2.f / (e + 1.f);
}
__device__ inline float4 bf4f(ushort4 u) {
    float4 f; f.x = bf2f(u.x); f.y = bf2f(u.y); f.z = bf2f(u.z); f.w = bf2f(u.w);
    return f;
}

// ---------- kernel 1: mask + bf16 cast + row norms; tail blocks do W transpose ----------
__global__ __launch_bounds__(128) void prep_kernel(
    const float* __restrict__ F0r, const float* __restrict__ F1r,
    const float* __restrict__ m0, const float* __restrict__ m1,
    const float* __restrict__ W0, const float* __restrict__ W1,
    u16* __restrict__ F0b, u16* __restrict__ F1b,
    u16* __restrict__ WT0, u16* __restrict__ WT1,
    float* __restrict__ sq0, float* __restrict__ sq1)
{
    int bx = blockIdx.x;
    int t = threadIdx.x;
    if (bx >= 16384) {
        // W [S,D] fp32 -> WT [D,S] bf16  (2*131072 elements, 2048 blocks)
        int idx = (bx - 16384) * 128 + t;
        int a = idx >> 17;
        int r = idx & 131071;
        int s = r >> 9, d = r & 511;
        const float* W = a ? W1 : W0;
        u16* WT = a ? WT1 : WT0;
        WT[d * 256 + s] = f2bf(W[r]);
        return;
    }
    int bs = bx;                  // b*256 + s
    size_t base = (size_t)bs * 512 + t * 4;
    float mk0 = m0[bs], mk1 = m1[bs];
    float4 v0 = *(const float4*)(F0r + base);
    float4 v1 = *(const float4*)(F1r + base);
    v0.x *= mk0; v0.y *= mk0; v0.z *= mk0; v0.w *= mk0;
    v1.x *= mk1; v1.y *= mk1; v1.z *= mk1; v1.w *= mk1;
    ushort4 u0; u0.x = f2bf(v0.x); u0.y = f2bf(v0.y); u0.z = f2bf(v0.z); u0.w = f2bf(v0.w);
    ushort4 u1; u1.x = f2bf(v1.x); u1.y = f2bf(v1.y); u1.z = f2bf(v1.z); u1.w = f2bf(v1.w);
    *(ushort4*)(F0b + base) = u0;
    *(ushort4*)(F1b + base) = u1;
    float s0p = v0.x*v0.x + v0.y*v0.y + v0.z*v0.z + v0.w*v0.w;
    float s1p = v1.x*v1.x + v1.y*v1.y + v1.z*v1.z + v1.w*v1.w;
    #pragma unroll
    for (int off = 32; off > 0; off >>= 1) {
        s0p += __shfl_xor(s0p, off);
        s1p += __shfl_xor(s1p, off);
    }
    __shared__ float red0[2], red1[2];
    if ((t & 63) == 0) { red0[t >> 6] = s0p; red1[t >> 6] = s1p; }
    __syncthreads();
    if (t == 0) { sq0[bs] = red0[0] + red0[1]; sq1[bs] = red1[0] + red1[1]; }
}

// ---------- kernel 2: cross-GEMM (64x64 tile, K=512, chunk 128); writes A and A^T ----------
// T14 async-stage: next 128-k panels are loaded into VGPRs during the current
// MFMA phase, so the global->LDS latency hides under compute instead of being
// exposed between barriers.
__global__ __launch_bounds__(256) void gemm_cross_kernel(
    const u16* __restrict__ F0b, const u16* __restrict__ F1b,
    const float* __restrict__ sq0, const float* __restrict__ sq1,
    u16* __restrict__ Abf, u16* __restrict__ ATbf)
{
    __shared__ __align__(16) u16 smem[64 * 136 * 2];   // As | Bs, 34.8 KB
    u16 (*As)[136] = (u16(*)[136])smem;
    u16 (*Bs)[136] = (u16(*)[136])(smem + 64 * 136);

    int b = blockIdx.y;
    int i0 = (blockIdx.x >> 2) * 64, j0 = (blockIdx.x & 3) * 64;
    const u16* Ap = F0b + (size_t)b * 131072;
    const u16* Bp = F1b + (size_t)b * 131072;
    const float* sqR = sq0 + b * 256;
    const float* sqC = sq1 + b * 256;

    const int t = threadIdx.x;
    const int lane = t & 63, w = t >> 6;
    const int wm = w >> 1, wn = w & 1;
    const int q = lane >> 4, lm = lane & 15;

    f32x4 acc[2][2];
    #pragma unroll
    for (int x = 0; x < 2; ++x)
        #pragma unroll
        for (int y = 0; y < 2; ++y)
            acc[x][y] = (f32x4){0.f, 0.f, 0.f, 0.f};

    // prologue: load first 128-k panels into regs
    uint4 ar[4], br[4];
    #pragma unroll
    for (int i = 0; i < 4; ++i) {
        int idx = i * 256 + t, row = idx >> 4, seg = idx & 15;
        ar[i] = *(const uint4*)(Ap + (size_t)(i0 + row) * 512 + seg * 8);
        br[i] = *(const uint4*)(Bp + (size_t)(j0 + row) * 512 + seg * 8);
    }

    for (int k0 = 0; k0 < 512; k0 += 128) {
        if (k0) __syncthreads();          // previous MFMA readers done
        #pragma unroll
        for (int i = 0; i < 4; ++i) {
            int idx = i * 256 + t, row = idx >> 4, seg = idx & 15;
            *(uint4*)&As[row][seg * 8] = ar[i];
            *(uint4*)&Bs[row][seg * 8] = br[i];
        }
        if (k0 + 128 < 512) {             // prefetch next panels (consumed after next barrier)
            #pragma unroll
            for (int i = 0; i < 4; ++i) {
                int idx = i * 256 + t, row = idx >> 4, seg = idx & 15;
                ar[i] = *(const uint4*)(Ap + (size_t)(i0 + row) * 512 + (k0 + 128) + seg * 8);
                br[i] = *(const uint4*)(Bp + (size_t)(j0 + row) * 512 + (k0 + 128) + seg * 8);
            }
        }
        __syncthreads();
        #pragma unroll
        for (int ks = 0; ks < 128; ks += 32) {
            short8 af[2], bfr[2];
            #pragma unroll
            for (int x = 0; x < 2; ++x) {
                af[x]  = *(const short8*)&As[wm * 32 + x * 16 + lm][ks + q * 8];
                bfr[x] = *(const short8*)&Bs[wn * 32 + x * 16 + lm][ks + q * 8];
            }
            #pragma unroll
            for (int x = 0; x < 2; ++x)
                #pragma unroll
                for (int y = 0; y < 2; ++y)
                    acc[x][y] = __builtin_amdgcn_mfma_f32_16x16x32_bf16(
                        af[x], bfr[y], acc[x][y], 0, 0, 0);
        }
    }
    __syncthreads();

    // epilogue: A values into LDS tile (alias As), then vectorized A and A^T stores
    u16 (*Ct)[136] = (u16(*)[136])smem;
    #pragma unroll
    for (int x = 0; x < 2; ++x) {
        #pragma unroll
        for (int r = 0; r < 4; ++r) {
            int ir = wm * 32 + x * 16 + q * 4 + r;
            float si = sqR[i0 + ir];
            #pragma unroll
            for (int y = 0; y < 2; ++y) {
                int jc = wn * 32 + y * 16 + lm;
                float d2 = si + sqC[j0 + jc] - 2.f * acc[x][y][r];
                d2 = fmaxf(d2, 0.f);
                float a = 1.f / (1.f + sqrtf(d2));
                Ct[ir][jc] = f2bf(a);
            }
        }
    }
    __syncthreads();

    u16* Aout  = Abf  + (size_t)b * 65536;
    u16* ATout = ATbf + (size_t)b * 65536;
    int ii = t >> 2;              // 0..63
    int c0 = (t & 3) * 16;        // 0,16,32,48
    #pragma unroll
    for (int c = 0; c < 4; ++c) { // A: row-major, vectorized
        ushort4 v = *(ushort4*)&Ct[ii][c0 + c * 4];
        *(ushort4*)&Aout[(size_t)(i0 + ii) * 256 + j0 + c0 + c * 4] = v;
    }
    #pragma unroll
    for (int c = 0; c < 4; ++c) { // A^T: transpose-read from LDS
        ushort4 v;
        v.x = Ct[c0 + c * 4 + 0][ii];
        v.y = Ct[c0 + c * 4 + 1][ii];
        v.z = Ct[c0 + c * 4 + 2][ii];
        v.w = Ct[c0 + c * 4 + 3][ii];
        *(ushort4*)&ATout[(size_t)(j0 + ii) * 256 + i0 + c0 + c * 4] = v;
    }
}

// ---------- kernel 3: fused Fa-GEMM + conv + tanh + avgpool ----------
// Block: 32 out rows x 512 d, one (batch, side). Fa never hits HBM.
// LDS diet: Al 36 rows, Fl aliased onto Bl (disjoint lifetimes) -> 37.9 KB,
// 4 blocks/CU possible. WT staging + conv F reads are register-prefetched so
// global latency hides under the MFMA phase (T14).
// NOTE: plain __launch_bounds__(256). (256,4) in the previous round capped
// VGPRs at 56 -> prefetch state spilled to scratch -> 180 MB of extra HBM
// writes per dispatch and a 35% slowdown. Natural footprint ~110 VGPR still
// allows 4 waves/SIMD; do NOT re-add a min-waves bound here.
__global__ __launch_bounds__(256) void fa_conv_kernel(
    const u16* __restrict__ Abf, const u16* __restrict__ ATbf,
    const u16* __restrict__ WT0, const u16* __restrict__ WT1,
    const u16* __restrict__ F0b, const u16* __restrict__ F1b,
    const float* __restrict__ cw, const float* __restrict__ cb,
    float* __restrict__ out)
{
    __shared__ __align__(16) u16 Al[36][264];     // A rows (36 used) x K=256, 19.0 KB
    __shared__ __align__(16) u16 BlFl[128 * 72];  // Bl [128][72] 18.4 KB; Fl [36][132] aliased
    u16 (*Bl)[72]  = (u16(*)[72])BlFl;
    u16 (*Fl)[132] = (u16(*)[132])BlFl;

    int b = blockIdx.y, side = blockIdx.z;
    int s0 = blockIdx.x * 32;
    const u16* Ap = (side ? Abf : ATbf) + (size_t)b * 65536;
    const u16* WT = side ? WT1 : WT0;
    const u16* Fb = (side ? F1b : F0b) + (size_t)b * 131072;
    float* o = out + (size_t)side * 8388608 + (size_t)b * 131072;

    const int t = threadIdx.x;
    const int lane = t & 63, w = t >> 6;
    const int q = lane >> 4, lm = lane & 15;

    // stage A once: rows r=0..35 <-> s = s0-2+r; zero when s OOB
    #pragma unroll
    for (int i = 0; i < 5; ++i) {
        int idx = i * 256 + t;          // 0..1279, use 0..1151
        if (idx < 1152) {
            int r = idx >> 5;           // 0..35
            int seg = idx & 31;         // 32 segs of 8 bf16
            int s = s0 - 2 + r;
            uint4 v = {0u, 0u, 0u, 0u};
            if ((unsigned)s < 256u)
                v = *(const uint4*)(Ap + (size_t)s * 256 + seg * 8);
            *(uint4*)&Al[r][seg * 8] = v;
        }
    }

    // A-fragment row pointers; x=2 rows >=36 are dead (outputs discarded) -> clamp to row 0
    const u16* aRow[3];
    aRow[0] = &Al[lm][0];
    aRow[1] = &Al[16 + lm][0];
    aRow[2] = &Al[(lm < 4) ? (32 + lm) : 0][0];

    float w00 = cw[0], w01 = cw[1], w02 = cw[2];
    float w10 = cw[3], w11 = cw[4], w12 = cw[5];
    float bias = cb[0];
    const float third = 1.f / 3.f;
    const int g = t >> 5;               // 0..7: out-row group (4 rows)
    const int dl = (t & 31) * 4;        // d within chunk

    // prologue: first WT chunk (n0=0, kb=0) into regs
    uint4 brg[4];
    #pragma unroll
    for (int i = 0; i < 4; ++i) {
        int idx = i * 256 + t, r = idx >> 3, seg = idx & 7;
        brg[i] = *(const uint4*)(WT + (size_t)r * 256 + seg * 8);
    }

    for (int n0 = 0; n0 < 512; n0 += 128) {
        // prefetch conv F reads for this d-chunk: hides under the whole GEMM phase
        ushort4 frg[8];
        #pragma unroll
        for (int k = 0; k < 8; ++k) {
            int s = s0 + g * 4 - 2 + k;
            ushort4 z = {0, 0, 0, 0};
            frg[k] = ((unsigned)s < 256u)
                   ? *(const ushort4*)(Fb + (size_t)s * 512 + n0 + dl) : z;
        }

        f32x4 acc[3][2];
        #pragma unroll
        for (int x = 0; x < 3; ++x)
            #pragma unroll
            for (int y = 0; y < 2; ++y)
                acc[x][y] = (f32x4){0.f, 0.f, 0.f, 0.f};

        for (int kb = 0; kb < 256; kb += 64) {
            __syncthreads();            // prior Bl/Fl readers done
            #pragma unroll
            for (int i = 0; i < 4; ++i) {
                int idx = i * 256 + t, r = idx >> 3, seg = idx & 7;
                *(uint4*)&Bl[r][seg * 8] = brg[i];
            }
            if (kb < 192) {             // prefetch next k-chunk during MFMA phase
                #pragma unroll
                for (int i = 0; i < 4; ++i) {
                    int idx = i * 256 + t, r = idx >> 3, seg = idx & 7;
                    brg[i] = *(const uint4*)(WT + (size_t)(n0 + r) * 256 + (kb + 64) + seg * 8);
                }
            }
            __syncthreads();
            #pragma unroll
            for (int ks = 0; ks < 64; ks += 32) {
                short8 af[3], bfr[2];
                #pragma unroll
                for (int x = 0; x < 3; ++x)
                    af[x] = *(const short8*)(aRow[x] + kb + ks + q * 8);
                #pragma unroll
                for (int y = 0; y < 2; ++y)
                    bfr[y] = *(const short8*)&Bl[w * 32 + y * 16 + lm][ks + q * 8];
                #pragma unroll
                for (int x = 0; x < 3; ++x)
                    #pragma unroll
                    for (int y = 0; y < 2; ++y)
                        acc[x][y] = __builtin_amdgcn_mfma_f32_16x16x32_bf16(
                            af[x], bfr[y], acc[x][y], 0, 0, 0);
            }
        }
        __syncthreads();                // Bl dead from here: Fl takes over the space

        // stage Fa (bf16) into LDS (aliases Bl)
        #pragma unroll
        for (int x = 0; x < 3; ++x)
            #pragma unroll
            for (int r = 0; r < 4; ++r) {
                int m = x * 16 + q * 4 + r;
                if (m < 36) {
                    #pragma unroll
                    for (int y = 0; y < 2; ++y)
                        Fl[m][w * 32 + y * 16 + lm] = f2bf(acc[x][y][r]);
                }
            }
        if (n0 < 384) {                 // prefetch next n0's first WT chunk during conv phase
            #pragma unroll
            for (int i = 0; i < 4; ++i) {
                int idx = i * 256 + t, r = idx >> 3, seg = idx & 7;
                brg[i] = *(const uint4*)(WT + (size_t)(n0 + 128 + r) * 256 + seg * 8);
            }
        }
        __syncthreads();

        // conv + tanh + avgpool for this 128-d chunk; thread: 4 out rows x 4 d
        float4 f[8], a[8];
        #pragma unroll
        for (int k = 0; k < 8; ++k) {
            f[k] = bf4f(frg[k]);
            a[k] = bf4f(*(const ushort4*)&Fl[g * 4 + k][dl]);
        }
        float4 ty[6];
        #pragma unroll
        for (int k = 0; k < 6; ++k) {
            float4 y;
            y.x = bias + w00*f[k].x + w01*f[k+1].x + w02*f[k+2].x + w10*a[k].x + w11*a[k+1].x + w12*a[k+2].x;
            y.y = bias + w00*f[k].y + w01*f[k+1].y + w02*f[k+2].y + w10*a[k].y + w11*a[k+1].y + w12*a[k+2].y;
            y.z = bias + w00*f[k].z + w01*f[k+1].z + w02*f[k+2].z + w10*a[k].z + w11*a[k+1].z + w12*a[k+2].z;
            y.w = bias + w00*f[k].w + w01*f[k+1].w + w02*f[k+2].w + w10*a[k].w + w11*a[k+1].w + w12*a[k+2].w;
            y.x = ftanh(y.x); y.y = ftanh(y.y); y.z = ftanh(y.z); y.w = ftanh(y.w);
            ty[k] = y;
        }
        #pragma unroll
        for (int r = 0; r < 4; ++r) {
            float4 res;
            res.x = (ty[r].x + ty[r+1].x + ty[r+2].x) * third;
            res.y = (ty[r].y + ty[r+1].y + ty[r+2].y) * third;
            res.z = (ty[r].z + ty[r+1].z + ty[r+2].z) * third;
            res.w = (ty[r].w + ty[r+1].w + ty[r+2].w) * third;
            *(float4*)(o + (size_t)(s0 + g * 4 + r) * 512 + n0 + dl) = res;
        }
        // next iteration's top-of-kb-loop barrier protects Fl before Bl overwrite
    }
}

// ---------- launcher ----------
extern "C" void kernel_launch(void* const* d_in, const int* in_sizes, int n_in,
                              void* d_out, int out_size, void* d_ws, size_t ws_size,
                              hipStream_t stream)
{
    const float* F0r = (const float*)d_in[0];
    const float* F1r = (const float*)d_in[1];
    const float* m0  = (const float*)d_in[2];
    const float* m1  = (const float*)d_in[3];
    const float* W0  = (const float*)d_in[4];
    const float* W1  = (const float*)d_in[5];
    const float* cw  = (const float*)d_in[6];
    const float* cb  = (const float*)d_in[7];
    float* out = (float*)d_out;

    char* ws = (char*)d_ws;
    u16* F0b   = (u16*)(ws);                      // 16 MiB  [B,S,D] bf16
    u16* F1b   = (u16*)(ws + 16777216);           // 16 MiB
    u16* Abf   = (u16*)(ws + 33554432);           // 8 MiB   [B,S,S] bf16
    u16* ATbf  = (u16*)(ws + 41943040);           // 8 MiB
    float* sq0 = (float*)(ws + 50331648);         // 64 KiB
    float* sq1 = (float*)(ws + 50397184);         // 64 KiB
    u16* WT0   = (u16*)(ws + 50462720);           // 256 KiB [D,S] bf16
    u16* WT1   = (u16*)(ws + 50724864);           // 256 KiB

    prep_kernel<<<18432, 128, 0, stream>>>(F0r, F1r, m0, m1, W0, W1,
                                           F0b, F1b, WT0, WT1, sq0, sq1);
    gemm_cross_kernel<<<dim3(16, 64), 256, 0, stream>>>(F0b, F1b, sq0, sq1, Abf, ATbf);
    fa_conv_kernel<<<dim3(8, 64, 2), 256, 0, stream>>>(Abf, ATbf, WT0, WT1,
                                                       F0b, F1b, cw, cb, out);
}

// Round 3
// 203.598 us; speedup vs baseline: 1.3564x; 1.3564x over previous
//
#include <hip/hip_runtime.h>

typedef unsigned short u16;
typedef __attribute__((ext_vector_type(8))) short short8;
typedef __attribute__((ext_vector_type(4))) float f32x4;

// ---------- helpers ----------
__device__ inline u16 f2bf(float f) {
    union { float f; unsigned u; } v; v.f = f;
    unsigned u = v.u;
    unsigned r = (u + 0x7FFFu + ((u >> 16) & 1u)) >> 16;
    return (u16)r;
}
__device__ inline float bf2f(u16 h) {
    union { unsigned u; float f; } v; v.u = ((unsigned)h) << 16;
    return v.f;
}
__device__ inline float ftanh(float x) {
    float e = __expf(2.f * x);
    return 1.f - 2.f / (e + 1.f);
}
__device__ inline float4 bf4f(ushort4 u) {
    float4 f; f.x = bf2f(u.x); f.y = bf2f(u.y); f.z = bf2f(u.z); f.w = bf2f(u.w);
    return f;
}

// ---------- kernel 1: mask + bf16 cast + row norms; tail blocks do W transpose ----------
__global__ __launch_bounds__(128) void prep_kernel(
    const float* __restrict__ F0r, const float* __restrict__ F1r,
    const float* __restrict__ m0, const float* __restrict__ m1,
    const float* __restrict__ W0, const float* __restrict__ W1,
    u16* __restrict__ F0b, u16* __restrict__ F1b,
    u16* __restrict__ WT0, u16* __restrict__ WT1,
    float* __restrict__ sq0, float* __restrict__ sq1)
{
    int bx = blockIdx.x;
    int t = threadIdx.x;
    if (bx >= 16384) {
        // W [S,D] fp32 -> WT [D,S] bf16  (2*131072 elements, 2048 blocks)
        int idx = (bx - 16384) * 128 + t;
        int a = idx >> 17;
        int r = idx & 131071;
        int s = r >> 9, d = r & 511;
        const float* W = a ? W1 : W0;
        u16* WT = a ? WT1 : WT0;
        WT[d * 256 + s] = f2bf(W[r]);
        return;
    }
    int bs = bx;                  // b*256 + s
    size_t base = (size_t)bs * 512 + t * 4;
    float mk0 = m0[bs], mk1 = m1[bs];
    float4 v0 = *(const float4*)(F0r + base);
    float4 v1 = *(const float4*)(F1r + base);
    v0.x *= mk0; v0.y *= mk0; v0.z *= mk0; v0.w *= mk0;
    v1.x *= mk1; v1.y *= mk1; v1.z *= mk1; v1.w *= mk1;
    ushort4 u0; u0.x = f2bf(v0.x); u0.y = f2bf(v0.y); u0.z = f2bf(v0.z); u0.w = f2bf(v0.w);
    ushort4 u1; u1.x = f2bf(v1.x); u1.y = f2bf(v1.y); u1.z = f2bf(v1.z); u1.w = f2bf(v1.w);
    *(ushort4*)(F0b + base) = u0;
    *(ushort4*)(F1b + base) = u1;
    float s0p = v0.x*v0.x + v0.y*v0.y + v0.z*v0.z + v0.w*v0.w;
    float s1p = v1.x*v1.x + v1.y*v1.y + v1.z*v1.z + v1.w*v1.w;
    #pragma unroll
    for (int off = 32; off > 0; off >>= 1) {
        s0p += __shfl_xor(s0p, off);
        s1p += __shfl_xor(s1p, off);
    }
    __shared__ float red0[2], red1[2];
    if ((t & 63) == 0) { red0[t >> 6] = s0p; red1[t >> 6] = s1p; }
    __syncthreads();
    if (t == 0) { sq0[bs] = red0[0] + red0[1]; sq1[bs] = red1[0] + red1[1]; }
}

// ---------- kernel 2: cross-GEMM (64x64 tile, K=512, chunk 128); writes A and A^T ----------
// Round-0 exact structure. NOTE: do NOT restructure staging into
// register-prefetch-across-barriers: hipcc drains vmcnt(0) at every
// __syncthreads, so cross-barrier prefetch hides nothing and the extra
// VGPR pressure cost ~31 us in rounds 1-2.
__global__ __launch_bounds__(256) void gemm_cross_kernel(
    const u16* __restrict__ F0b, const u16* __restrict__ F1b,
    const float* __restrict__ sq0, const float* __restrict__ sq1,
    u16* __restrict__ Abf, u16* __restrict__ ATbf)
{
    __shared__ __align__(16) u16 smem[64 * 136 * 2];   // As | Bs, 34.8 KB
    u16 (*As)[136] = (u16(*)[136])smem;
    u16 (*Bs)[136] = (u16(*)[136])(smem + 64 * 136);

    int b = blockIdx.y;
    int i0 = (blockIdx.x >> 2) * 64, j0 = (blockIdx.x & 3) * 64;
    const u16* Ap = F0b + (size_t)b * 131072;
    const u16* Bp = F1b + (size_t)b * 131072;
    const float* sqR = sq0 + b * 256;
    const float* sqC = sq1 + b * 256;

    const int t = threadIdx.x;
    const int lane = t & 63, w = t >> 6;
    const int wm = w >> 1, wn = w & 1;
    const int q = lane >> 4, lm = lane & 15;

    f32x4 acc[2][2];
    #pragma unroll
    for (int x = 0; x < 2; ++x)
        #pragma unroll
        for (int y = 0; y < 2; ++y)
            acc[x][y] = (f32x4){0.f, 0.f, 0.f, 0.f};

    for (int k0 = 0; k0 < 512; k0 += 128) {
        #pragma unroll
        for (int i = 0; i < 4; ++i) {
            int idx = i * 256 + t;       // 0..1023
            int row = idx >> 4;          // 0..63
            int seg = idx & 15;          // 16 segs of 8 bf16 per 128-k row
            *(uint4*)&As[row][seg * 8] =
                *(const uint4*)(Ap + (size_t)(i0 + row) * 512 + k0 + seg * 8);
            *(uint4*)&Bs[row][seg * 8] =
                *(const uint4*)(Bp + (size_t)(j0 + row) * 512 + k0 + seg * 8);
        }
        __syncthreads();
        #pragma unroll
        for (int ks = 0; ks < 128; ks += 32) {
            short8 af[2], bfr[2];
            #pragma unroll
            for (int x = 0; x < 2; ++x) {
                af[x]  = *(const short8*)&As[wm * 32 + x * 16 + lm][ks + q * 8];
                bfr[x] = *(const short8*)&Bs[wn * 32 + x * 16 + lm][ks + q * 8];
            }
            #pragma unroll
            for (int x = 0; x < 2; ++x)
                #pragma unroll
                for (int y = 0; y < 2; ++y)
                    acc[x][y] = __builtin_amdgcn_mfma_f32_16x16x32_bf16(
                        af[x], bfr[y], acc[x][y], 0, 0, 0);
        }
        __syncthreads();
    }

    // epilogue: A values into LDS tile (alias As), then vectorized A and A^T stores
    u16 (*Ct)[136] = (u16(*)[136])smem;
    #pragma unroll
    for (int x = 0; x < 2; ++x) {
        #pragma unroll
        for (int r = 0; r < 4; ++r) {
            int ir = wm * 32 + x * 16 + q * 4 + r;
            float si = sqR[i0 + ir];
            #pragma unroll
            for (int y = 0; y < 2; ++y) {
                int jc = wn * 32 + y * 16 + lm;
                float d2 = si + sqC[j0 + jc] - 2.f * acc[x][y][r];
                d2 = fmaxf(d2, 0.f);
                float a = 1.f / (1.f + sqrtf(d2));
                Ct[ir][jc] = f2bf(a);
            }
        }
    }
    __syncthreads();

    u16* Aout  = Abf  + (size_t)b * 65536;
    u16* ATout = ATbf + (size_t)b * 65536;
    int ii = t >> 2;              // 0..63
    int c0 = (t & 3) * 16;        // 0,16,32,48
    #pragma unroll
    for (int c = 0; c < 4; ++c) { // A: row-major, vectorized
        ushort4 v = *(ushort4*)&Ct[ii][c0 + c * 4];
        *(ushort4*)&Aout[(size_t)(i0 + ii) * 256 + j0 + c0 + c * 4] = v;
    }
    #pragma unroll
    for (int c = 0; c < 4; ++c) { // A^T: transpose-read from LDS
        ushort4 v;
        v.x = Ct[c0 + c * 4 + 0][ii];
        v.y = Ct[c0 + c * 4 + 1][ii];
        v.z = Ct[c0 + c * 4 + 2][ii];
        v.w = Ct[c0 + c * 4 + 3][ii];
        *(ushort4*)&ATout[(size_t)(j0 + ii) * 256 + i0 + c0 + c * 4] = v;
    }
}

// ---------- kernel 3: fused Fa-GEMM + conv + tanh + avgpool ----------
// Round-0 register structure (stage global->reg->ds_write inside the phase;
// NO cross-barrier reg prefetch -- hipcc drains vmcnt at every barrier, so
// prefetch hides nothing and the VGPR pressure caused spills in rounds 1-2:
// WRITE_SIZE 64->150/245 MB of scratch traffic).
// Kept from rounds 1-2 (numerically verified): LDS diet -- Al 36 rows with
// clamped dead fragment rows, Fl aliased onto Bl (disjoint lifetimes,
// barrier-separated). LDS 53.7 -> 37.9 KB => 4 blocks/CU (vs 2 in round 0),
// doubling the TLP that covers the barrier-drain stalls.
__global__ __launch_bounds__(256) void fa_conv_kernel(
    const u16* __restrict__ Abf, const u16* __restrict__ ATbf,
    const u16* __restrict__ WT0, const u16* __restrict__ WT1,
    const u16* __restrict__ F0b, const u16* __restrict__ F1b,
    const float* __restrict__ cw, const float* __restrict__ cb,
    float* __restrict__ out)
{
    __shared__ __align__(16) u16 Al[36][264];     // A rows (36 used) x K=256, 19.0 KB
    __shared__ __align__(16) u16 BlFl[128 * 72];  // Bl [128][72] 18.4 KB; Fl [36][132] aliased
    u16 (*Bl)[72]  = (u16(*)[72])BlFl;
    u16 (*Fl)[132] = (u16(*)[132])BlFl;

    int b = blockIdx.y, side = blockIdx.z;
    int s0 = blockIdx.x * 32;
    const u16* Ap = (side ? Abf : ATbf) + (size_t)b * 65536;
    const u16* WT = side ? WT1 : WT0;
    const u16* Fb = (side ? F1b : F0b) + (size_t)b * 131072;
    float* o = out + (size_t)side * 8388608 + (size_t)b * 131072;

    const int t = threadIdx.x;
    const int lane = t & 63, w = t >> 6;
    const int q = lane >> 4, lm = lane & 15;

    // stage A once: rows r=0..35 <-> s = s0-2+r; zero when s OOB
    #pragma unroll
    for (int i = 0; i < 5; ++i) {
        int idx = i * 256 + t;          // 0..1279, use 0..1151
        if (idx < 1152) {
            int r = idx >> 5;           // 0..35
            int seg = idx & 31;         // 32 segs of 8 bf16
            int s = s0 - 2 + r;
            uint4 v = {0u, 0u, 0u, 0u};
            if ((unsigned)s < 256u)
                v = *(const uint4*)(Ap + (size_t)s * 256 + seg * 8);
            *(uint4*)&Al[r][seg * 8] = v;
        }
    }

    // A-fragment row pointers; x=2 rows >=36 are dead (outputs discarded) -> clamp to row 0
    const u16* aRow[3];
    aRow[0] = &Al[lm][0];
    aRow[1] = &Al[16 + lm][0];
    aRow[2] = &Al[(lm < 4) ? (32 + lm) : 0][0];

    float w00 = cw[0], w01 = cw[1], w02 = cw[2];
    float w10 = cw[3], w11 = cw[4], w12 = cw[5];
    float bias = cb[0];
    const float third = 1.f / 3.f;
    const int g = t >> 5;               // 0..7: out-row group (4 rows)
    const int dl = (t & 31) * 4;        // d within chunk

    for (int n0 = 0; n0 < 512; n0 += 128) {
        f32x4 acc[3][2];
        #pragma unroll
        for (int x = 0; x < 3; ++x)
            #pragma unroll
            for (int y = 0; y < 2; ++y)
                acc[x][y] = (f32x4){0.f, 0.f, 0.f, 0.f};

        for (int kb = 0; kb < 256; kb += 64) {
            // protects: prior MFMA reads of Bl (kb>0) or prior conv reads of Fl (n0>0)
            __syncthreads();
            #pragma unroll
            for (int i = 0; i < 4; ++i) {
                int idx = i * 256 + t;   // 0..1023
                int r = idx >> 3;        // 0..127 (d row)
                int seg = idx & 7;
                *(uint4*)&Bl[r][seg * 8] =
                    *(const uint4*)(WT + (size_t)(n0 + r) * 256 + kb + seg * 8);
            }
            __syncthreads();
            #pragma unroll
            for (int ks = 0; ks < 64; ks += 32) {
                short8 af[3], bfr[2];
                #pragma unroll
                for (int x = 0; x < 3; ++x)
                    af[x] = *(const short8*)(aRow[x] + kb + ks + q * 8);
                #pragma unroll
                for (int y = 0; y < 2; ++y)
                    bfr[y] = *(const short8*)&Bl[w * 32 + y * 16 + lm][ks + q * 8];
                #pragma unroll
                for (int x = 0; x < 3; ++x)
                    #pragma unroll
                    for (int y = 0; y < 2; ++y)
                        acc[x][y] = __builtin_amdgcn_mfma_f32_16x16x32_bf16(
                            af[x], bfr[y], acc[x][y], 0, 0, 0);
            }
        }
        __syncthreads();                // last MFMA done; Bl dead: Fl takes over the space

        // stage Fa (bf16) into LDS (aliases Bl)
        #pragma unroll
        for (int x = 0; x < 3; ++x)
            #pragma unroll
            for (int r = 0; r < 4; ++r) {
                int m = x * 16 + q * 4 + r;
                if (m < 36) {
                    #pragma unroll
                    for (int y = 0; y < 2; ++y)
                        Fl[m][w * 32 + y * 16 + lm] = f2bf(acc[x][y][r]);
                }
            }
        __syncthreads();

        // conv + tanh + avgpool for this 128-d chunk; thread: 4 out rows x 4 d
        float4 f[8], a[8];
        #pragma unroll
        for (int k = 0; k < 8; ++k) {
            int s = s0 + g * 4 - 2 + k;
            if ((unsigned)s < 256u)
                f[k] = bf4f(*(const ushort4*)(Fb + (size_t)s * 512 + n0 + dl));
            else
                f[k] = make_float4(0.f, 0.f, 0.f, 0.f);
            a[k] = bf4f(*(const ushort4*)&Fl[g * 4 + k][dl]);
        }
        float4 ty[6];
        #pragma unroll
        for (int k = 0; k < 6; ++k) {
            float4 y;
            y.x = bias + w00*f[k].x + w01*f[k+1].x + w02*f[k+2].x + w10*a[k].x + w11*a[k+1].x + w12*a[k+2].x;
            y.y = bias + w00*f[k].y + w01*f[k+1].y + w02*f[k+2].y + w10*a[k].y + w11*a[k+1].y + w12*a[k+2].y;
            y.z = bias + w00*f[k].z + w01*f[k+1].z + w02*f[k+2].z + w10*a[k].z + w11*a[k+1].z + w12*a[k+2].z;
            y.w = bias + w00*f[k].w + w01*f[k+1].w + w02*f[k+2].w + w10*a[k].w + w11*a[k+1].w + w12*a[k+2].w;
            y.x = ftanh(y.x); y.y = ftanh(y.y); y.z = ftanh(y.z); y.w = ftanh(y.w);
            ty[k] = y;
        }
        #pragma unroll
        for (int r = 0; r < 4; ++r) {
            float4 res;
            res.x = (ty[r].x + ty[r+1].x + ty[r+2].x) * third;
            res.y = (ty[r].y + ty[r+1].y + ty[r+2].y) * third;
            res.z = (ty[r].z + ty[r+1].z + ty[r+2].z) * third;
            res.w = (ty[r].w + ty[r+1].w + ty[r+2].w) * third;
            *(float4*)(o + (size_t)(s0 + g * 4 + r) * 512 + n0 + dl) = res;
        }
        // next iteration's top-of-kb-loop barrier protects Fl before Bl overwrite
    }
}

// ---------- launcher ----------
extern "C" void kernel_launch(void* const* d_in, const int* in_sizes, int n_in,
                              void* d_out, int out_size, void* d_ws, size_t ws_size,
                              hipStream_t stream)
{
    const float* F0r = (const float*)d_in[0];
    const float* F1r = (const float*)d_in[1];
    const float* m0  = (const float*)d_in[2];
    const float* m1  = (const float*)d_in[3];
    const float* W0  = (const float*)d_in[4];
    const float* W1  = (const float*)d_in[5];
    const float* cw  = (const float*)d_in[6];
    const float* cb  = (const float*)d_in[7];
    float* out = (float*)d_out;

    char* ws = (char*)d_ws;
    u16* F0b   = (u16*)(ws);                      // 16 MiB  [B,S,D] bf16
    u16* F1b   = (u16*)(ws + 16777216);           // 16 MiB
    u16* Abf   = (u16*)(ws + 33554432);           // 8 MiB   [B,S,S] bf16
    u16* ATbf  = (u16*)(ws + 41943040);           // 8 MiB
    float* sq0 = (float*)(ws + 50331648);         // 64 KiB
    float* sq1 = (float*)(ws + 50397184);         // 64 KiB
    u16* WT0   = (u16*)(ws + 50462720);           // 256 KiB [D,S] bf16
    u16* WT1   = (u16*)(ws + 50724864);           // 256 KiB

    prep_kernel<<<18432, 128, 0, stream>>>(F0r, F1r, m0, m1, W0, W1,
                                           F0b, F1b, WT0, WT1, sq0, sq1);
    gemm_cross_kernel<<<dim3(16, 64), 256, 0, stream>>>(F0b, F1b, sq0, sq1, Abf, ATbf);
    fa_conv_kernel<<<dim3(8, 64, 2), 256, 0, stream>>>(Abf, ATbf, WT0, WT1,
                                                       F0b, F1b, cw, cb, out);
}

// Round 4
// 201.439 us; speedup vs baseline: 1.3709x; 1.0107x over previous
//
#include <hip/hip_runtime.h>

typedef unsigned short u16;
typedef __attribute__((ext_vector_type(8))) short short8;
typedef __attribute__((ext_vector_type(4))) float f32x4;

// ---------- helpers ----------
__device__ inline u16 f2bf(float f) {
    union { float f; unsigned u; } v; v.f = f;
    unsigned u = v.u;
    unsigned r = (u + 0x7FFFu + ((u >> 16) & 1u)) >> 16;
    return (u16)r;
}
__device__ inline float bf2f(u16 h) {
    union { unsigned u; float f; } v; v.u = ((unsigned)h) << 16;
    return v.f;
}
__device__ inline float ftanh(float x) {
    float e = __expf(2.f * x);
    return 1.f - 2.f / (e + 1.f);
}
__device__ inline float4 bf4f(ushort4 u) {
    float4 f; f.x = bf2f(u.x); f.y = bf2f(u.y); f.z = bf2f(u.z); f.w = bf2f(u.w);
    return f;
}

// 16B async global->LDS. LDS dest is wave-uniform base + lane*16 (HW pattern);
// global src is per-lane. Zero VGPR staging cost -- this is what makes
// cross-barrier prefetch spill-free (rounds 1-2 failed on reg-staged prefetch).
typedef const __attribute__((address_space(1))) void* gas_ptr;
typedef __attribute__((address_space(3))) void* las_ptr;
__device__ __forceinline__ void gl2lds16(const u16* g, u16* l) {
    __builtin_amdgcn_global_load_lds((gas_ptr)(const void*)g, (las_ptr)(void*)l, 16, 0, 0);
}

// ---------- kernel 1: mask + bf16 cast + row norms; tail blocks do W transpose ----------
__global__ __launch_bounds__(128) void prep_kernel(
    const float* __restrict__ F0r, const float* __restrict__ F1r,
    const float* __restrict__ m0, const float* __restrict__ m1,
    const float* __restrict__ W0, const float* __restrict__ W1,
    u16* __restrict__ F0b, u16* __restrict__ F1b,
    u16* __restrict__ WT0, u16* __restrict__ WT1,
    float* __restrict__ sq0, float* __restrict__ sq1)
{
    int bx = blockIdx.x;
    int t = threadIdx.x;
    if (bx >= 16384) {
        // W [S,D] fp32 -> WT [D,S] bf16  (2*131072 elements, 2048 blocks)
        int idx = (bx - 16384) * 128 + t;
        int a = idx >> 17;
        int r = idx & 131071;
        int s = r >> 9, d = r & 511;
        const float* W = a ? W1 : W0;
        u16* WT = a ? WT1 : WT0;
        WT[d * 256 + s] = f2bf(W[r]);
        return;
    }
    int bs = bx;                  // b*256 + s
    size_t base = (size_t)bs * 512 + t * 4;
    float mk0 = m0[bs], mk1 = m1[bs];
    float4 v0 = *(const float4*)(F0r + base);
    float4 v1 = *(const float4*)(F1r + base);
    v0.x *= mk0; v0.y *= mk0; v0.z *= mk0; v0.w *= mk0;
    v1.x *= mk1; v1.y *= mk1; v1.z *= mk1; v1.w *= mk1;
    ushort4 u0; u0.x = f2bf(v0.x); u0.y = f2bf(v0.y); u0.z = f2bf(v0.z); u0.w = f2bf(v0.w);
    ushort4 u1; u1.x = f2bf(v1.x); u1.y = f2bf(v1.y); u1.z = f2bf(v1.z); u1.w = f2bf(v1.w);
    *(ushort4*)(F0b + base) = u0;
    *(ushort4*)(F1b + base) = u1;
    float s0p = v0.x*v0.x + v0.y*v0.y + v0.z*v0.z + v0.w*v0.w;
    float s1p = v1.x*v1.x + v1.y*v1.y + v1.z*v1.z + v1.w*v1.w;
    #pragma unroll
    for (int off = 32; off > 0; off >>= 1) {
        s0p += __shfl_xor(s0p, off);
        s1p += __shfl_xor(s1p, off);
    }
    __shared__ float red0[2], red1[2];
    if ((t & 63) == 0) { red0[t >> 6] = s0p; red1[t >> 6] = s1p; }
    __syncthreads();
    if (t == 0) { sq0[bs] = red0[0] + red0[1]; sq1[bs] = red1[0] + red1[1]; }
}

// ---------- kernel 2: cross-GEMM (64x64 tile, K=512, chunk 128); writes A and A^T ----------
// T3-minimum 2-phase schedule with global_load_lds (m97 structure):
//   STAGE(buf0,c0); for c: { barrier(drains stage c, hidden under prior MFMA);
//                            STAGE(buf^1, c+1); ds_read+MFMA(buf c); }
// One barrier per chunk (was 2); staging needs no VGPRs.
// LDS rows are UNPADDED (global_load_lds writes linearly); bank conflicts on
// the fragment reads are fixed by a both-sides XOR swizzle (rule #21):
// stage source chunk seg^(row&7), read slot u^(lm&7); row&7==lm&7 for all
// fragment rows, 16 lanes spread over 8 x 16B slots -> 2-way = free.
__global__ __launch_bounds__(256) void gemm_cross_kernel(
    const u16* __restrict__ F0b, const u16* __restrict__ F1b,
    const float* __restrict__ sq0, const float* __restrict__ sq1,
    u16* __restrict__ Abf, u16* __restrict__ ATbf)
{
    // As0 | Bs0 | As1 | Bs1, each [64][128] u16 unpadded = 16 KB; total 64 KB
    __shared__ __align__(16) u16 smem[4 * 8192];

    int b = blockIdx.y;
    int i0 = (blockIdx.x >> 2) * 64, j0 = (blockIdx.x & 3) * 64;
    const u16* Ap = F0b + (size_t)b * 131072;
    const u16* Bp = F1b + (size_t)b * 131072;
    const float* sqR = sq0 + b * 256;
    const float* sqC = sq1 + b * 256;

    const int t = threadIdx.x;
    const int lane = t & 63, w = t >> 6;
    const int wm = w >> 1, wn = w & 1;
    const int q = lane >> 4, lm = lane & 15;

#define STAGE_AB(bufo, k0) do {                                                \
    _Pragma("unroll")                                                          \
    for (int i_ = 0; i_ < 4; ++i_) {                                           \
        int idx_ = i_ * 256 + t;                                               \
        int row_ = idx_ >> 4, seg_ = idx_ & 15;                                \
        int ss_  = seg_ ^ (row_ & 7);                                          \
        int lo_  = (bufo) + (i_ * 256 + w * 64) * 8;  /* wave-uniform */       \
        gl2lds16(Ap + (size_t)(i0 + row_) * 512 + (k0) + ss_ * 8,              \
                 &smem[lo_]);                                                  \
        gl2lds16(Bp + (size_t)(j0 + row_) * 512 + (k0) + ss_ * 8,              \
                 &smem[lo_ + 8192]);                                           \
    } } while (0)

    f32x4 acc[2][2];
    #pragma unroll
    for (int x = 0; x < 2; ++x)
        #pragma unroll
        for (int y = 0; y < 2; ++y)
            acc[x][y] = (f32x4){0.f, 0.f, 0.f, 0.f};

    STAGE_AB(0, 0);                     // prologue: chunk 0 -> buf0

    #pragma unroll
    for (int c = 0; c < 4; ++c) {
        __syncthreads();                // drains stage c (in flight during prior MFMA)
        if (c < 3)
            STAGE_AB(((c + 1) & 1) * 16384, (c + 1) * 128);   // issue next FIRST
        const int cb = (c & 1) * 16384;
        #pragma unroll
        for (int ks = 0; ks < 128; ks += 32) {
            short8 af[2], bfr[2];
            #pragma unroll
            for (int x = 0; x < 2; ++x) {
                int ra = wm * 32 + x * 16 + lm;
                int rb = wn * 32 + x * 16 + lm;
                int su = (((ks >> 3) + q) ^ (lm & 7)) * 8;    // read-side swizzle
                af[x]  = *(const short8*)&smem[cb + ra * 128 + su];
                bfr[x] = *(const short8*)&smem[cb + 8192 + rb * 128 + su];
            }
            #pragma unroll
            for (int x = 0; x < 2; ++x)
                #pragma unroll
                for (int y = 0; y < 2; ++y)
                    acc[x][y] = __builtin_amdgcn_mfma_f32_16x16x32_bf16(
                        af[x], bfr[y], acc[x][y], 0, 0, 0);
        }
    }
    __syncthreads();                    // all MFMA reads done; smem reusable
#undef STAGE_AB

    // epilogue: A values into LDS tile (alias smem, padded 136 for transpose), then stores
    u16 (*Ct)[136] = (u16(*)[136])smem;
    #pragma unroll
    for (int x = 0; x < 2; ++x) {
        #pragma unroll
        for (int r = 0; r < 4; ++r) {
            int ir = wm * 32 + x * 16 + q * 4 + r;
            float si = sqR[i0 + ir];
            #pragma unroll
            for (int y = 0; y < 2; ++y) {
                int jc = wn * 32 + y * 16 + lm;
                float d2 = si + sqC[j0 + jc] - 2.f * acc[x][y][r];
                d2 = fmaxf(d2, 0.f);
                float a = 1.f / (1.f + sqrtf(d2));
                Ct[ir][jc] = f2bf(a);
            }
        }
    }
    __syncthreads();

    u16* Aout  = Abf  + (size_t)b * 65536;
    u16* ATout = ATbf + (size_t)b * 65536;
    int ii = t >> 2;              // 0..63
    int c0 = (t & 3) * 16;        // 0,16,32,48
    #pragma unroll
    for (int c = 0; c < 4; ++c) { // A: row-major, vectorized
        ushort4 v = *(ushort4*)&Ct[ii][c0 + c * 4];
        *(ushort4*)&Aout[(size_t)(i0 + ii) * 256 + j0 + c0 + c * 4] = v;
    }
    #pragma unroll
    for (int c = 0; c < 4; ++c) { // A^T: transpose-read from LDS
        ushort4 v;
        v.x = Ct[c0 + c * 4 + 0][ii];
        v.y = Ct[c0 + c * 4 + 1][ii];
        v.z = Ct[c0 + c * 4 + 2][ii];
        v.w = Ct[c0 + c * 4 + 3][ii];
        *(ushort4*)&ATout[(size_t)(j0 + ii) * 256 + i0 + c0 + c * 4] = v;
    }
}

// ---------- kernel 3: fused Fa-GEMM + conv + tanh + avgpool ----------
// Same T3-minimum schedule for the WT staging: Bl double-buffered unpadded
// [128][64] (global_load_lds + XOR swizzle), ONE barrier per kb chunk (was 2),
// 5 barriers per n0 (was 10). Next-n0's first chunk is issued at the top of
// the conv phase so its latency hides under conv. Fl is its own buffer.
__global__ __launch_bounds__(256) void fa_conv_kernel(
    const u16* __restrict__ Abf, const u16* __restrict__ ATbf,
    const u16* __restrict__ WT0, const u16* __restrict__ WT1,
    const u16* __restrict__ F0b, const u16* __restrict__ F1b,
    const float* __restrict__ cw, const float* __restrict__ cb,
    float* __restrict__ out)
{
    __shared__ __align__(16) u16 Al[36][264];    // A rows x K=256 (padded), 19.0 KB
    __shared__ __align__(16) u16 BlBuf[2 * 8192];// 2 x [128][64] u16 unpadded, 32 KB
    __shared__ __align__(16) u16 Fl[36][132];    // Fa staging, 9.3 KB

    int b = blockIdx.y, side = blockIdx.z;
    int s0 = blockIdx.x * 32;
    const u16* Ap = (side ? Abf : ATbf) + (size_t)b * 65536;
    const u16* WT = side ? WT1 : WT0;
    const u16* Fb = (side ? F1b : F0b) + (size_t)b * 131072;
    float* o = out + (size_t)side * 8388608 + (size_t)b * 131072;

    const int t = threadIdx.x;
    const int lane = t & 63, w = t >> 6;
    const int q = lane >> 4, lm = lane & 15;

#define STAGE_B(bufo, nn, kb) do {                                             \
    _Pragma("unroll")                                                          \
    for (int i_ = 0; i_ < 4; ++i_) {                                           \
        int idx_ = i_ * 256 + t;                                               \
        int r_ = idx_ >> 3, seg_ = idx_ & 7;                                   \
        int ss_ = seg_ ^ (r_ & 7);                                             \
        gl2lds16(WT + (size_t)((nn) + r_) * 256 + (kb) + ss_ * 8,              \
                 &BlBuf[(bufo) + (i_ * 256 + w * 64) * 8]);                    \
    } } while (0)

    // stage A once: rows r=0..35 <-> s = s0-2+r; zero when s OOB
    #pragma unroll
    for (int i = 0; i < 5; ++i) {
        int idx = i * 256 + t;          // 0..1279, use 0..1151
        if (idx < 1152) {
            int r = idx >> 5;           // 0..35
            int seg = idx & 31;         // 32 segs of 8 bf16
            int s = s0 - 2 + r;
            uint4 v = {0u, 0u, 0u, 0u};
            if ((unsigned)s < 256u)
                v = *(const uint4*)(Ap + (size_t)s * 256 + seg * 8);
            *(uint4*)&Al[r][seg * 8] = v;
        }
    }

    // A-fragment row pointers; x=2 rows >=36 are dead (outputs discarded) -> clamp to row 0
    const u16* aRow[3];
    aRow[0] = &Al[lm][0];
    aRow[1] = &Al[16 + lm][0];
    aRow[2] = &Al[(lm < 4) ? (32 + lm) : 0][0];

    float w00 = cw[0], w01 = cw[1], w02 = cw[2];
    float w10 = cw[3], w11 = cw[4], w12 = cw[5];
    float bias = cb[0];
    const float third = 1.f / 3.f;
    const int g = t >> 5;               // 0..7: out-row group (4 rows)
    const int dl = (t & 31) * 4;        // d within chunk

    STAGE_B(0, 0, 0);                   // prologue: n0=0, kb=0 -> buf0

    for (int n0 = 0; n0 < 512; n0 += 128) {
        f32x4 acc[3][2];
        #pragma unroll
        for (int x = 0; x < 3; ++x)
            #pragma unroll
            for (int y = 0; y < 2; ++y)
                acc[x][y] = (f32x4){0.f, 0.f, 0.f, 0.f};

        #pragma unroll
        for (int kb_i = 0; kb_i < 4; ++kb_i) {
            __syncthreads();            // drains stage kb_i (hidden under prior phase)
            if (kb_i < 3)
                STAGE_B(((kb_i + 1) & 1) * 8192, n0, (kb_i + 1) * 64);
            const int cbuf = (kb_i & 1) * 8192;
            const int kb = kb_i * 64;
            #pragma unroll
            for (int ks = 0; ks < 64; ks += 32) {
                short8 af[3], bfr[2];
                #pragma unroll
                for (int x = 0; x < 3; ++x)
                    af[x] = *(const short8*)(aRow[x] + kb + ks + q * 8);
                #pragma unroll
                for (int y = 0; y < 2; ++y) {
                    int rb = w * 32 + y * 16 + lm;
                    int su = (((ks >> 3) + q) ^ (lm & 7)) * 8;   // read-side swizzle
                    bfr[y] = *(const short8*)&BlBuf[cbuf + rb * 64 + su];
                }
                #pragma unroll
                for (int x = 0; x < 3; ++x)
                    #pragma unroll
                    for (int y = 0; y < 2; ++y)
                        acc[x][y] = __builtin_amdgcn_mfma_f32_16x16x32_bf16(
                            af[x], bfr[y], acc[x][y], 0, 0, 0);
            }
        }

        // stage Fa (bf16) into Fl (own buffer; no aliasing)
        #pragma unroll
        for (int x = 0; x < 3; ++x)
            #pragma unroll
            for (int r = 0; r < 4; ++r) {
                int m = x * 16 + q * 4 + r;
                if (m < 36) {
                    #pragma unroll
                    for (int y = 0; y < 2; ++y)
                        Fl[m][w * 32 + y * 16 + lm] = f2bf(acc[x][y][r]);
                }
            }
        __syncthreads();                // Fl visible to all waves

        // issue next n0's first WT chunk now: latency hides under conv phase,
        // drained at next n0's kb_i=0 barrier. buf0 safe: all kb reads done.
        if (n0 < 384)
            STAGE_B(0, n0 + 128, 0);

        // conv + tanh + avgpool for this 128-d chunk; thread: 4 out rows x 4 d
        float4 f[8], a[8];
        #pragma unroll
        for (int k = 0; k < 8; ++k) {
            int s = s0 + g * 4 - 2 + k;
            if ((unsigned)s < 256u)
                f[k] = bf4f(*(const ushort4*)(Fb + (size_t)s * 512 + n0 + dl));
            else
                f[k] = make_float4(0.f, 0.f, 0.f, 0.f);
            a[k] = bf4f(*(const ushort4*)&Fl[g * 4 + k][dl]);
        }
        float4 ty[6];
        #pragma unroll
        for (int k = 0; k < 6; ++k) {
            float4 y;
            y.x = bias + w00*f[k].x + w01*f[k+1].x + w02*f[k+2].x + w10*a[k].x + w11*a[k+1].x + w12*a[k+2].x;
            y.y = bias + w00*f[k].y + w01*f[k+1].y + w02*f[k+2].y + w10*a[k].y + w11*a[k+1].y + w12*a[k+2].y;
            y.z = bias + w00*f[k].z + w01*f[k+1].z + w02*f[k+2].z + w10*a[k].z + w11*a[k+1].z + w12*a[k+2].z;
            y.w = bias + w00*f[k].w + w01*f[k+1].w + w02*f[k+2].w + w10*a[k].w + w11*a[k+1].w + w12*a[k+2].w;
            y.x = ftanh(y.x); y.y = ftanh(y.y); y.z = ftanh(y.z); y.w = ftanh(y.w);
            ty[k] = y;
        }
        #pragma unroll
        for (int r = 0; r < 4; ++r) {
            float4 res;
            res.x = (ty[r].x + ty[r+1].x + ty[r+2].x) * third;
            res.y = (ty[r].y + ty[r+1].y + ty[r+2].y) * third;
            res.z = (ty[r].z + ty[r+1].z + ty[r+2].z) * third;
            res.w = (ty[r].w + ty[r+1].w + ty[r+2].w) * third;
            *(float4*)(o + (size_t)(s0 + g * 4 + r) * 512 + n0 + dl) = res;
        }
        // next n0's kb_i=0 barrier separates conv reads of Fl from its rewrite
    }
#undef STAGE_B
}

// ---------- launcher ----------
extern "C" void kernel_launch(void* const* d_in, const int* in_sizes, int n_in,
                              void* d_out, int out_size, void* d_ws, size_t ws_size,
                              hipStream_t stream)
{
    const float* F0r = (const float*)d_in[0];
    const float* F1r = (const float*)d_in[1];
    const float* m0  = (const float*)d_in[2];
    const float* m1  = (const float*)d_in[3];
    const float* W0  = (const float*)d_in[4];
    const float* W1  = (const float*)d_in[5];
    const float* cw  = (const float*)d_in[6];
    const float* cb  = (const float*)d_in[7];
    float* out = (float*)d_out;

    char* ws = (char*)d_ws;
    u16* F0b   = (u16*)(ws);                      // 16 MiB  [B,S,D] bf16
    u16* F1b   = (u16*)(ws + 16777216);           // 16 MiB
    u16* Abf   = (u16*)(ws + 33554432);           // 8 MiB   [B,S,S] bf16
    u16* ATbf  = (u16*)(ws + 41943040);           // 8 MiB
    float* sq0 = (float*)(ws + 50331648);         // 64 KiB
    float* sq1 = (float*)(ws + 50397184);         // 64 KiB
    u16* WT0   = (u16*)(ws + 50462720);           // 256 KiB [D,S] bf16
    u16* WT1   = (u16*)(ws + 50724864);           // 256 KiB

    prep_kernel<<<18432, 128, 0, stream>>>(F0r, F1r, m0, m1, W0, W1,
                                           F0b, F1b, WT0, WT1, sq0, sq1);
    gemm_cross_kernel<<<dim3(16, 64), 256, 0, stream>>>(F0b, F1b, sq0, sq1, Abf, ATbf);
    fa_conv_kernel<<<dim3(8, 64, 2), 256, 0, stream>>>(Abf, ATbf, WT0, WT1,
                                                       F0b, F1b, cw, cb, out);
}

// Round 5
// 184.323 us; speedup vs baseline: 1.4982x; 1.0929x over previous
//
#include <hip/hip_runtime.h>

typedef unsigned short u16;
typedef __attribute__((ext_vector_type(8))) short short8;
typedef __attribute__((ext_vector_type(4))) float f32x4;

// ---------- helpers ----------
__device__ inline u16 f2bf(float f) {
    union { float f; unsigned u; } v; v.f = f;
    unsigned u = v.u;
    unsigned r = (u + 0x7FFFu + ((u >> 16) & 1u)) >> 16;
    return (u16)r;
}
__device__ inline float bf2f(u16 h) {
    union { unsigned u; float f; } v; v.u = ((unsigned)h) << 16;
    return v.f;
}
// fast rcp/sqrt (v_rcp_f32 / v_sqrt_f32, ~2^-21 rel err; tolerance is bf16-level
// 0.0078 so this is free). Without these, hipcc emits the ~10-inst IEEE div
// sequence per '/' -- ~96 divs/thread in fa_conv was a big slice of VALUBusy=38%.
__device__ inline float frcp(float x) { return __builtin_amdgcn_rcpf(x); }
__device__ inline float fsqrt(float x) { return __builtin_amdgcn_sqrtf(x); }
__device__ inline float ftanh(float x) {
    float e = __expf(2.f * x);
    return 1.f - 2.f * frcp(e + 1.f);   // x>>0: e=inf, rcp=0 -> 1; x<<0: e=0 -> -1
}
__device__ inline float4 bf4f(ushort4 u) {
    float4 f; f.x = bf2f(u.x); f.y = bf2f(u.y); f.z = bf2f(u.z); f.w = bf2f(u.w);
    return f;
}

// 16B async global->LDS. LDS dest is wave-uniform base + lane*16 (HW pattern);
// global src is per-lane. Zero VGPR staging cost.
typedef const __attribute__((address_space(1))) void* gas_ptr;
typedef __attribute__((address_space(3))) void* las_ptr;
__device__ __forceinline__ void gl2lds16(const u16* g, u16* l) {
    __builtin_amdgcn_global_load_lds((gas_ptr)(const void*)g, (las_ptr)(void*)l, 16, 0, 0);
}

// ---------- kernel 1: mask + bf16 cast + row norms; tail blocks do W transpose ----------
// Tail rewritten as LDS-tiled transpose: the old version did 262144 scattered
// 2B stores at 512B stride (64 cache lines per wave per store). Now reads are
// float4-coalesced rows of W and writes are ushort4-coalesced rows of WT.
__global__ __launch_bounds__(128) void prep_kernel(
    const float* __restrict__ F0r, const float* __restrict__ F1r,
    const float* __restrict__ m0, const float* __restrict__ m1,
    const float* __restrict__ W0, const float* __restrict__ W1,
    u16* __restrict__ F0b, u16* __restrict__ F1b,
    u16* __restrict__ WT0, u16* __restrict__ WT1,
    float* __restrict__ sq0, float* __restrict__ sq1)
{
    int bx = blockIdx.x;
    int t = threadIdx.x;
    if (bx >= 16384) {
        // W [256 s][512 d] fp32 -> WT [512 d][256 s] bf16, via [32 s][64 d] LDS tiles.
        // 2 arrays x 8 s-tiles x 8 d-tiles = 128 tail blocks.
        __shared__ u16 Wl[64][40];          // pad 40: 8B-aligned rows, ~2-way banks
        int idx2 = bx - 16384;
        int a = idx2 >> 6;                  // 0..1
        int tile = idx2 & 63;
        int s0 = (tile >> 3) * 32, d0 = (tile & 7) * 64;
        const float* W = a ? W1 : W0;
        u16* WT = a ? WT1 : WT0;
        #pragma unroll
        for (int i = 0; i < 4; ++i) {
            int idx = i * 512 + t * 4;      // 0..2047
            int sl = idx >> 6, dl = idx & 63;
            float4 v = *(const float4*)(W + (size_t)(s0 + sl) * 512 + d0 + dl);
            Wl[dl + 0][sl] = f2bf(v.x);
            Wl[dl + 1][sl] = f2bf(v.y);
            Wl[dl + 2][sl] = f2bf(v.z);
            Wl[dl + 3][sl] = f2bf(v.w);
        }
        __syncthreads();
        #pragma unroll
        for (int i = 0; i < 4; ++i) {
            int idx = i * 512 + t * 4;
            int dl = idx >> 5, sl = idx & 31;
            ushort4 v;
            v.x = Wl[dl][sl + 0]; v.y = Wl[dl][sl + 1];
            v.z = Wl[dl][sl + 2]; v.w = Wl[dl][sl + 3];
            *(ushort4*)(WT + (size_t)(d0 + dl) * 256 + s0 + sl) = v;
        }
        return;
    }
    int bs = bx;                  // b*256 + s
    size_t base = (size_t)bs * 512 + t * 4;
    float mk0 = m0[bs], mk1 = m1[bs];
    float4 v0 = *(const float4*)(F0r + base);
    float4 v1 = *(const float4*)(F1r + base);
    v0.x *= mk0; v0.y *= mk0; v0.z *= mk0; v0.w *= mk0;
    v1.x *= mk1; v1.y *= mk1; v1.z *= mk1; v1.w *= mk1;
    ushort4 u0; u0.x = f2bf(v0.x); u0.y = f2bf(v0.y); u0.z = f2bf(v0.z); u0.w = f2bf(v0.w);
    ushort4 u1; u1.x = f2bf(v1.x); u1.y = f2bf(v1.y); u1.z = f2bf(v1.z); u1.w = f2bf(v1.w);
    *(ushort4*)(F0b + base) = u0;
    *(ushort4*)(F1b + base) = u1;
    float s0p = v0.x*v0.x + v0.y*v0.y + v0.z*v0.z + v0.w*v0.w;
    float s1p = v1.x*v1.x + v1.y*v1.y + v1.z*v1.z + v1.w*v1.w;
    #pragma unroll
    for (int off = 32; off > 0; off >>= 1) {
        s0p += __shfl_xor(s0p, off);
        s1p += __shfl_xor(s1p, off);
    }
    __shared__ float red0[2], red1[2];
    if ((t & 63) == 0) { red0[t >> 6] = s0p; red1[t >> 6] = s1p; }
    __syncthreads();
    if (t == 0) { sq0[bs] = red0[0] + red0[1]; sq1[bs] = red1[0] + red1[1]; }
}

// ---------- kernel 2: cross-GEMM (64x64 tile, K=512, chunk 128); writes A and A^T ----------
// T3-minimum 2-phase schedule with global_load_lds (m97 structure), one barrier
// per chunk, both-sides XOR swizzle (verified round 4: bank conflicts -40%).
__global__ __launch_bounds__(256) void gemm_cross_kernel(
    const u16* __restrict__ F0b, const u16* __restrict__ F1b,
    const float* __restrict__ sq0, const float* __restrict__ sq1,
    u16* __restrict__ Abf, u16* __restrict__ ATbf)
{
    // As0 | Bs0 | As1 | Bs1, each [64][128] u16 unpadded = 16 KB; total 64 KB
    __shared__ __align__(16) u16 smem[4 * 8192];

    int b = blockIdx.y;
    int i0 = (blockIdx.x >> 2) * 64, j0 = (blockIdx.x & 3) * 64;
    const u16* Ap = F0b + (size_t)b * 131072;
    const u16* Bp = F1b + (size_t)b * 131072;
    const float* sqR = sq0 + b * 256;
    const float* sqC = sq1 + b * 256;

    const int t = threadIdx.x;
    const int lane = t & 63, w = t >> 6;
    const int wm = w >> 1, wn = w & 1;
    const int q = lane >> 4, lm = lane & 15;

#define STAGE_AB(bufo, k0) do {                                                \
    _Pragma("unroll")                                                          \
    for (int i_ = 0; i_ < 4; ++i_) {                                           \
        int idx_ = i_ * 256 + t;                                               \
        int row_ = idx_ >> 4, seg_ = idx_ & 15;                                \
        int ss_  = seg_ ^ (row_ & 7);                                          \
        int lo_  = (bufo) + (i_ * 256 + w * 64) * 8;  /* wave-uniform */       \
        gl2lds16(Ap + (size_t)(i0 + row_) * 512 + (k0) + ss_ * 8,              \
                 &smem[lo_]);                                                  \
        gl2lds16(Bp + (size_t)(j0 + row_) * 512 + (k0) + ss_ * 8,              \
                 &smem[lo_ + 8192]);                                           \
    } } while (0)

    f32x4 acc[2][2];
    #pragma unroll
    for (int x = 0; x < 2; ++x)
        #pragma unroll
        for (int y = 0; y < 2; ++y)
            acc[x][y] = (f32x4){0.f, 0.f, 0.f, 0.f};

    STAGE_AB(0, 0);                     // prologue: chunk 0 -> buf0

    #pragma unroll
    for (int c = 0; c < 4; ++c) {
        __syncthreads();                // drains stage c (in flight during prior MFMA)
        if (c < 3)
            STAGE_AB(((c + 1) & 1) * 16384, (c + 1) * 128);   // issue next FIRST
        const int cb = (c & 1) * 16384;
        #pragma unroll
        for (int ks = 0; ks < 128; ks += 32) {
            short8 af[2], bfr[2];
            #pragma unroll
            for (int x = 0; x < 2; ++x) {
                int ra = wm * 32 + x * 16 + lm;
                int rb = wn * 32 + x * 16 + lm;
                int su = (((ks >> 3) + q) ^ (lm & 7)) * 8;    // read-side swizzle
                af[x]  = *(const short8*)&smem[cb + ra * 128 + su];
                bfr[x] = *(const short8*)&smem[cb + 8192 + rb * 128 + su];
            }
            #pragma unroll
            for (int x = 0; x < 2; ++x)
                #pragma unroll
                for (int y = 0; y < 2; ++y)
                    acc[x][y] = __builtin_amdgcn_mfma_f32_16x16x32_bf16(
                        af[x], bfr[y], acc[x][y], 0, 0, 0);
        }
    }
    __syncthreads();                    // all MFMA reads done; smem reusable
#undef STAGE_AB

    // epilogue: A values into LDS tile (alias smem, padded 136 for transpose), then stores
    u16 (*Ct)[136] = (u16(*)[136])smem;
    #pragma unroll
    for (int x = 0; x < 2; ++x) {
        #pragma unroll
        for (int r = 0; r < 4; ++r) {
            int ir = wm * 32 + x * 16 + q * 4 + r;
            float si = sqR[i0 + ir];
            #pragma unroll
            for (int y = 0; y < 2; ++y) {
                int jc = wn * 32 + y * 16 + lm;
                float d2 = si + sqC[j0 + jc] - 2.f * acc[x][y][r];
                d2 = fmaxf(d2, 0.f);
                float a = frcp(1.f + fsqrt(d2));   // was IEEE sqrt+div (~18 insts)
                Ct[ir][jc] = f2bf(a);
            }
        }
    }
    __syncthreads();

    u16* Aout  = Abf  + (size_t)b * 65536;
    u16* ATout = ATbf + (size_t)b * 65536;
    int ii = t >> 2;              // 0..63
    int c0 = (t & 3) * 16;        // 0,16,32,48
    #pragma unroll
    for (int c = 0; c < 4; ++c) { // A: row-major, vectorized
        ushort4 v = *(ushort4*)&Ct[ii][c0 + c * 4];
        *(ushort4*)&Aout[(size_t)(i0 + ii) * 256 + j0 + c0 + c * 4] = v;
    }
    #pragma unroll
    for (int c = 0; c < 4; ++c) { // A^T: transpose-read from LDS
        ushort4 v;
        v.x = Ct[c0 + c * 4 + 0][ii];
        v.y = Ct[c0 + c * 4 + 1][ii];
        v.z = Ct[c0 + c * 4 + 2][ii];
        v.w = Ct[c0 + c * 4 + 3][ii];
        *(ushort4*)&ATout[(size_t)(j0 + ii) * 256 + i0 + c0 + c * 4] = v;
    }
}

// ---------- kernel 3: fused Fa-GEMM + conv + tanh + avgpool ----------
// Round-4 structure (global_load_lds double-buffered WT staging, 1 barrier per
// kb chunk). This round: fast-rcp tanh (cuts the dominant VALUBusy), and the
// conv F-loads are issued BEFORE the Fl-write phase so their latency hides
// under the f2bf/ds_write VALU work and the barrier drain (costs 8 VGPRs
// across one barrier -- no spill risk at 88->~96 vs the 256 budget).
__global__ __launch_bounds__(256) void fa_conv_kernel(
    const u16* __restrict__ Abf, const u16* __restrict__ ATbf,
    const u16* __restrict__ WT0, const u16* __restrict__ WT1,
    const u16* __restrict__ F0b, const u16* __restrict__ F1b,
    const float* __restrict__ cw, const float* __restrict__ cb,
    float* __restrict__ out)
{
    __shared__ __align__(16) u16 Al[36][264];    // A rows x K=256 (padded), 19.0 KB
    __shared__ __align__(16) u16 BlBuf[2 * 8192];// 2 x [128][64] u16 unpadded, 32 KB
    __shared__ __align__(16) u16 Fl[36][132];    // Fa staging, 9.3 KB

    int b = blockIdx.y, side = blockIdx.z;
    int s0 = blockIdx.x * 32;
    const u16* Ap = (side ? Abf : ATbf) + (size_t)b * 65536;
    const u16* WT = side ? WT1 : WT0;
    const u16* Fb = (side ? F1b : F0b) + (size_t)b * 131072;
    float* o = out + (size_t)side * 8388608 + (size_t)b * 131072;

    const int t = threadIdx.x;
    const int lane = t & 63, w = t >> 6;
    const int q = lane >> 4, lm = lane & 15;

#define STAGE_B(bufo, nn, kb) do {                                             \
    _Pragma("unroll")                                                          \
    for (int i_ = 0; i_ < 4; ++i_) {                                           \
        int idx_ = i_ * 256 + t;                                               \
        int r_ = idx_ >> 3, seg_ = idx_ & 7;                                   \
        int ss_ = seg_ ^ (r_ & 7);                                             \
        gl2lds16(WT + (size_t)((nn) + r_) * 256 + (kb) + ss_ * 8,              \
                 &BlBuf[(bufo) + (i_ * 256 + w * 64) * 8]);                    \
    } } while (0)

    // stage A once: rows r=0..35 <-> s = s0-2+r; zero when s OOB
    #pragma unroll
    for (int i = 0; i < 5; ++i) {
        int idx = i * 256 + t;          // 0..1279, use 0..1151
        if (idx < 1152) {
            int r = idx >> 5;           // 0..35
            int seg = idx & 31;         // 32 segs of 8 bf16
            int s = s0 - 2 + r;
            uint4 v = {0u, 0u, 0u, 0u};
            if ((unsigned)s < 256u)
                v = *(const uint4*)(Ap + (size_t)s * 256 + seg * 8);
            *(uint4*)&Al[r][seg * 8] = v;
        }
    }

    // A-fragment row pointers; x=2 rows >=36 are dead (outputs discarded) -> clamp to row 0
    const u16* aRow[3];
    aRow[0] = &Al[lm][0];
    aRow[1] = &Al[16 + lm][0];
    aRow[2] = &Al[(lm < 4) ? (32 + lm) : 0][0];

    float w00 = cw[0], w01 = cw[1], w02 = cw[2];
    float w10 = cw[3], w11 = cw[4], w12 = cw[5];
    float bias = cb[0];
    const float third = 1.f / 3.f;
    const int g = t >> 5;               // 0..7: out-row group (4 rows)
    const int dl = (t & 31) * 4;        // d within chunk

    STAGE_B(0, 0, 0);                   // prologue: n0=0, kb=0 -> buf0

    for (int n0 = 0; n0 < 512; n0 += 128) {
        f32x4 acc[3][2];
        #pragma unroll
        for (int x = 0; x < 3; ++x)
            #pragma unroll
            for (int y = 0; y < 2; ++y)
                acc[x][y] = (f32x4){0.f, 0.f, 0.f, 0.f};

        #pragma unroll
        for (int kb_i = 0; kb_i < 4; ++kb_i) {
            __syncthreads();            // drains stage kb_i (hidden under prior phase)
            if (kb_i < 3)
                STAGE_B(((kb_i + 1) & 1) * 8192, n0, (kb_i + 1) * 64);
            const int cbuf = (kb_i & 1) * 8192;
            const int kb = kb_i * 64;
            #pragma unroll
            for (int ks = 0; ks < 64; ks += 32) {
                short8 af[3], bfr[2];
                #pragma unroll
                for (int x = 0; x < 3; ++x)
                    af[x] = *(const short8*)(aRow[x] + kb + ks + q * 8);
                #pragma unroll
                for (int y = 0; y < 2; ++y) {
                    int rb = w * 32 + y * 16 + lm;
                    int su = (((ks >> 3) + q) ^ (lm & 7)) * 8;   // read-side swizzle
                    bfr[y] = *(const short8*)&BlBuf[cbuf + rb * 64 + su];
                }
                #pragma unroll
                for (int x = 0; x < 3; ++x)
                    #pragma unroll
                    for (int y = 0; y < 2; ++y)
                        acc[x][y] = __builtin_amdgcn_mfma_f32_16x16x32_bf16(
                            af[x], bfr[y], acc[x][y], 0, 0, 0);
            }
        }

        // issue conv F-loads NOW: latency overlaps the Fl-write VALU phase below
        // and is drained by the barrier (cannot sink past it -- __syncthreads is
        // a memory fence). Consumed after the barrier.
        ushort4 frg[8];
        #pragma unroll
        for (int k = 0; k < 8; ++k) {
            int s = s0 + g * 4 - 2 + k;
            ushort4 z = {0, 0, 0, 0};
            frg[k] = ((unsigned)s < 256u)
                   ? *(const ushort4*)(Fb + (size_t)s * 512 + n0 + dl) : z;
        }

        // stage Fa (bf16) into Fl (own buffer; no aliasing)
        #pragma unroll
        for (int x = 0; x < 3; ++x)
            #pragma unroll
            for (int r = 0; r < 4; ++r) {
                int m = x * 16 + q * 4 + r;
                if (m < 36) {
                    #pragma unroll
                    for (int y = 0; y < 2; ++y)
                        Fl[m][w * 32 + y * 16 + lm] = f2bf(acc[x][y][r]);
                }
            }
        __syncthreads();                // Fl visible to all waves; frg complete

        // issue next n0's first WT chunk now: latency hides under conv phase,
        // drained at next n0's kb_i=0 barrier. buf0 safe: all kb reads done.
        if (n0 < 384)
            STAGE_B(0, n0 + 128, 0);

        // conv + tanh + avgpool for this 128-d chunk; thread: 4 out rows x 4 d
        float4 f[8], a[8];
        #pragma unroll
        for (int k = 0; k < 8; ++k) {
            f[k] = bf4f(frg[k]);
            a[k] = bf4f(*(const ushort4*)&Fl[g * 4 + k][dl]);
        }
        float4 ty[6];
        #pragma unroll
        for (int k = 0; k < 6; ++k) {
            float4 y;
            y.x = bias + w00*f[k].x + w01*f[k+1].x + w02*f[k+2].x + w10*a[k].x + w11*a[k+1].x + w12*a[k+2].x;
            y.y = bias + w00*f[k].y + w01*f[k+1].y + w02*f[k+2].y + w10*a[k].y + w11*a[k+1].y + w12*a[k+2].y;
            y.z = bias + w00*f[k].z + w01*f[k+1].z + w02*f[k+2].z + w10*a[k].z + w11*a[k+1].z + w12*a[k+2].z;
            y.w = bias + w00*f[k].w + w01*f[k+1].w + w02*f[k+2].w + w10*a[k].w + w11*a[k+1].w + w12*a[k+2].w;
            y.x = ftanh(y.x); y.y = ftanh(y.y); y.z = ftanh(y.z); y.w = ftanh(y.w);
            ty[k] = y;
        }
        #pragma unroll
        for (int r = 0; r < 4; ++r) {
            float4 res;
            res.x = (ty[r].x + ty[r+1].x + ty[r+2].x) * third;
            res.y = (ty[r].y + ty[r+1].y + ty[r+2].y) * third;
            res.z = (ty[r].z + ty[r+1].z + ty[r+2].z) * third;
            res.w = (ty[r].w + ty[r+1].w + ty[r+2].w) * third;
            *(float4*)(o + (size_t)(s0 + g * 4 + r) * 512 + n0 + dl) = res;
        }
        // next n0's kb_i=0 barrier separates conv reads of Fl from its rewrite
    }
#undef STAGE_B
}

// ---------- launcher ----------
extern "C" void kernel_launch(void* const* d_in, const int* in_sizes, int n_in,
                              void* d_out, int out_size, void* d_ws, size_t ws_size,
                              hipStream_t stream)
{
    const float* F0r = (const float*)d_in[0];
    const float* F1r = (const float*)d_in[1];
    const float* m0  = (const float*)d_in[2];
    const float* m1  = (const float*)d_in[3];
    const float* W0  = (const float*)d_in[4];
    const float* W1  = (const float*)d_in[5];
    const float* cw  = (const float*)d_in[6];
    const float* cb  = (const float*)d_in[7];
    float* out = (float*)d_out;

    char* ws = (char*)d_ws;
    u16* F0b   = (u16*)(ws);                      // 16 MiB  [B,S,D] bf16
    u16* F1b   = (u16*)(ws + 16777216);           // 16 MiB
    u16* Abf   = (u16*)(ws + 33554432);           // 8 MiB   [B,S,S] bf16
    u16* ATbf  = (u16*)(ws + 41943040);           // 8 MiB
    float* sq0 = (float*)(ws + 50331648);         // 64 KiB
    float* sq1 = (float*)(ws + 50397184);         // 64 KiB
    u16* WT0   = (u16*)(ws + 50462720);           // 256 KiB [D,S] bf16
    u16* WT1   = (u16*)(ws + 50724864);           // 256 KiB

    // main 16384 blocks + 128 transpose-tile tail blocks
    prep_kernel<<<16512, 128, 0, stream>>>(F0r, F1r, m0, m1, W0, W1,
                                           F0b, F1b, WT0, WT1, sq0, sq1);
    gemm_cross_kernel<<<dim3(16, 64), 256, 0, stream>>>(F0b, F1b, sq0, sq1, Abf, ATbf);
    fa_conv_kernel<<<dim3(8, 64, 2), 256, 0, stream>>>(Abf, ATbf, WT0, WT1,
                                                       F0b, F1b, cw, cb, out);
}